// Round 3
// baseline (6470.416 us; speedup 1.0000x reference)
//
#include <hip/hip_runtime.h>
#include <cmath>

#define RN 512
#define RT 1024
#define RB 64

// 256 blocks x 512 threads, 4 blocks per batch (same-XCD grouping via bid%8).
// Each block owns 128 output rows. Thread (q=tid>>4, c16=tid&15) holds
// W[rowbase+4q+i][c16*32..+31] for i=0..3 as 32 NAMED float4 VGPR variables
// (no array -> no SROA limit -> no scratch spill). The previous step's
// tanh(h) row is read directly from outH (global, L2/L1-hot) -- no LDS at all.
// Cross-block sync: per-batch monotonic atomic counter, release/acquire agent
// scope; outH row address is unique per step so no double-buffer hazard.

#define DECLW(r) float4 w##r##_0, w##r##_1, w##r##_2, w##r##_3, w##r##_4, w##r##_5, w##r##_6, w##r##_7;

#define LOADW(r,j) { float4 v = *reinterpret_cast<const float4*>(Wr##r + (j)*4); \
    asm volatile("" : "+v"(v.x), "+v"(v.y), "+v"(v.z), "+v"(v.w)); \
    w##r##_##j = v; }

#define FMA4(r,j,tv) \
    d##r = fmaf(w##r##_##j.x, (tv).x, d##r); \
    d##r = fmaf(w##r##_##j.y, (tv).y, d##r); \
    d##r = fmaf(w##r##_##j.z, (tv).z, d##r); \
    d##r = fmaf(w##r##_##j.w, (tv).w, d##r);

#define STEPJ(j,tv) FMA4(0,j,tv) FMA4(1,j,tv) FMA4(2,j,tv) FMA4(3,j,tv)

__global__ void __launch_bounds__(512, 2) rnn_step_kernel(
    const float* __restrict__ h0,
    const float* __restrict__ X,
    const float* __restrict__ W,
    const float* __restrict__ tanh0,
    float* __restrict__ outH,
    unsigned int* __restrict__ ctr)
{
    const int bid  = blockIdx.x;
    const int xcd  = bid & 7;
    const int slot = bid >> 3;               // 0..31
    const int batch = xcd * 8 + (slot >> 2); // 0..63
    const int part  = slot & 3;              // 0..3
    const int rowbase = part * 128;

    const int tid = threadIdx.x;
    const int q   = tid >> 4;                // 0..31 : row-quad within slice
    const int c16 = tid & 15;                // 0..15 : 32-wide k-chunk

    DECLW(0) DECLW(1) DECLW(2) DECLW(3)

    {
        const float* Wr0 = W + (size_t)(rowbase + q*4 + 0) * RN + c16*32;
        const float* Wr1 = W + (size_t)(rowbase + q*4 + 1) * RN + c16*32;
        const float* Wr2 = W + (size_t)(rowbase + q*4 + 2) * RN + c16*32;
        const float* Wr3 = W + (size_t)(rowbase + q*4 + 3) * RN + c16*32;
        LOADW(0,0) LOADW(0,1) LOADW(0,2) LOADW(0,3) LOADW(0,4) LOADW(0,5) LOADW(0,6) LOADW(0,7)
        LOADW(1,0) LOADW(1,1) LOADW(1,2) LOADW(1,3) LOADW(1,4) LOADW(1,5) LOADW(1,6) LOADW(1,7)
        LOADW(2,0) LOADW(2,1) LOADW(2,2) LOADW(2,3) LOADW(2,4) LOADW(2,5) LOADW(2,6) LOADW(2,7)
        LOADW(3,0) LOADW(3,1) LOADW(3,2) LOADW(3,3) LOADW(3,4) LOADW(3,5) LOADW(3,6) LOADW(3,7)
    }

    const bool owner = (c16 < 4);
    const int myrow = rowbase + q * 4 + c16;   // valid when owner
    float h = 0.f, xv = 0.f;
    if (owner) {
        h  = h0[myrow];
        xv = X[(size_t)batch * RT * RN + myrow];   // x for t=0
    }

    unsigned int* myctr = ctr + batch * 32;    // 128B stride per batch

    const float* outBase = outH + (size_t)batch * RT * RN;

    #pragma unroll 1
    for (int t = 0; t < RT; ++t) {
        // source of tanh(h_t): precomputed tanh(h0) for t=0, else previous
        // step's output row (released by all 4 blocks before we got here)
        const float* src = (t == 0) ? tanh0 : (outBase + (size_t)(t - 1) * RN);
        const float4* sp = reinterpret_cast<const float4*>(src + c16 * 32);
        float4 t0 = sp[0], t1 = sp[1], t2 = sp[2], t3 = sp[3];
        float4 t4 = sp[4], t5 = sp[5], t6 = sp[6], t7 = sp[7];

        float d0 = 0.f, d1 = 0.f, d2 = 0.f, d3 = 0.f;
        STEPJ(0,t0) STEPJ(1,t1) STEPJ(2,t2) STEPJ(3,t3)
        STEPJ(4,t4) STEPJ(5,t5) STEPJ(6,t6) STEPJ(7,t7)

        // reduce across the 16 c16-lanes (xor stays inside the 16-lane group)
        #pragma unroll
        for (int m = 1; m <= 8; m <<= 1) {
            d0 += __shfl_xor(d0, m);
            d1 += __shfl_xor(d1, m);
            d2 += __shfl_xor(d2, m);
            d3 += __shfl_xor(d3, m);
        }

        if (owner) {
            const float dot = (c16 == 0) ? d0 : (c16 == 1) ? d1 : (c16 == 2) ? d2 : d3;
            h = 0.9f * h + 0.1f * (dot + xv);
            const float th = tanhf(h);
            outH[((size_t)batch * RT + t) * RN + myrow] = th;
            if (t + 1 < RT)   // prefetch next x; latency hides under barrier
                xv = X[((size_t)batch * RT + (t + 1)) * RN + myrow];
        }

        if (t + 1 < RT) {
            __syncthreads();   // drains each wave's vmcnt: th stores in L2
            if (tid == 0) {
                __hip_atomic_fetch_add(myctr, 1u, __ATOMIC_RELEASE, __HIP_MEMORY_SCOPE_AGENT);
                const unsigned int target = 4u * (unsigned)(t + 1);
                while (__hip_atomic_load(myctr, __ATOMIC_ACQUIRE, __HIP_MEMORY_SCOPE_AGENT) < target) {
                    __builtin_amdgcn_s_sleep(1);
                }
            }
            __syncthreads();   // broadcast barrier completion
        }
    }
}

// geometry epilogue: geo[b,t,:] = hidden[b,t,:] @ Gw^T + Gb ; one wave per (b,t)
__global__ void geom_kernel(const float* __restrict__ hid,
                            const float* __restrict__ Gw,
                            const float* __restrict__ Gb,
                            float* __restrict__ geo)
{
    const int wid  = (blockIdx.x * blockDim.x + threadIdx.x) >> 6;
    const int lane = threadIdx.x & 63;
    if (wid >= RB * RT) return;
    const float* rowp = hid + (size_t)wid * RN;
    float g0 = 0.f, g1 = 0.f;
    #pragma unroll
    for (int j = 0; j < 8; ++j) {
        float v = rowp[lane + 64 * j];
        g0 = fmaf(v, Gw[lane + 64 * j], g0);
        g1 = fmaf(v, Gw[RN + lane + 64 * j], g1);
    }
    #pragma unroll
    for (int m = 32; m >= 1; m >>= 1) {
        g0 += __shfl_xor(g0, m);
        g1 += __shfl_xor(g1, m);
    }
    if (lane == 0) {
        geo[(size_t)wid * 2]     = g0 + Gb[0];
        geo[(size_t)wid * 2 + 1] = g1 + Gb[1];
    }
}

// per-launch init: tanh(h0) table + zeroed barrier counters (ws is poisoned,
// never re-poisoned -> must re-init every launch; deterministic)
__global__ void init_misc(const float* __restrict__ h0,
                          float* __restrict__ tanh0,
                          unsigned int* __restrict__ ctr)
{
    int i = blockIdx.x * blockDim.x + threadIdx.x;
    if (i < RN) tanh0[i] = tanhf(h0[i]);
    if (i < RB * 32) ctr[i] = 0u;
}

extern "C" void kernel_launch(void* const* d_in, const int* in_sizes, int n_in,
                              void* d_out, int out_size, void* d_ws, size_t ws_size,
                              hipStream_t stream)
{
    const float* h0 = (const float*)d_in[0];
    const float* X  = (const float*)d_in[1];
    const float* W  = (const float*)d_in[2];
    const float* Gw = (const float*)d_in[3];
    const float* Gb = (const float*)d_in[4];

    float* outH = (float*)d_out;
    float* geo  = outH + (size_t)RB * RT * RN;

    float* tanh0 = (float*)d_ws;                       // 512 floats
    unsigned int* ctr = (unsigned int*)d_ws + RN;      // 64*32 uints

    init_misc<<<4, 512, 0, stream>>>(h0, tanh0, ctr);

    void* kargs[] = { (void*)&h0, (void*)&X, (void*)&W, (void*)&tanh0,
                      (void*)&outH, (void*)&ctr };
    hipLaunchCooperativeKernel(rnn_step_kernel, dim3(256), dim3(512), kargs, 0, stream);

    geom_kernel<<<(RB * RT * 64 + 255) / 256, 256, 0, stream>>>(outH, Gw, Gb, geo);
}